// Round 16
// baseline (247.639 us; speedup 1.0000x reference)
//
#include <hip/hip_runtime.h>
#include <hip/hip_bf16.h>
#include <hip/hip_cooperative_groups.h>

namespace cg = cooperative_groups;

#define BB 16
#define TE 512
#define TD 64
#define HE 512

// 2*log2(e): folded into Ws/Uh GEMM epilogue (with exp2) so the scores inner
// loop needs no exp at all: tanh term via 1/(Ew*Eu+1).
#define PRESCALE 2.8853900817779268f

typedef __attribute__((ext_vector_type(8))) short bf16x8;
typedef __attribute__((ext_vector_type(4))) float f32x4;

__device__ __forceinline__ float fexp2(float x) {
#if __has_builtin(__builtin_amdgcn_exp2f)
    return __builtin_amdgcn_exp2f(x);
#else
    return exp2f(x);
#endif
}
__device__ __forceinline__ float frcp(float x) {
#if __has_builtin(__builtin_amdgcn_rcpf)
    return __builtin_amdgcn_rcpf(x);
#else
    return __fdividef(1.f, x);
#endif
}

// split fp32 -> bf16 hi + bf16 lo (x ~= hi + lo, ~2^-17 relative)
__device__ __forceinline__ void split2(float x, unsigned short& h, unsigned short& l) {
    __hip_bfloat16 hb = __float2bfloat16(x);
    h = *(unsigned short*)&hb;
    float r = x - __bfloat162float(hb);
    __hip_bfloat16 lb = __float2bfloat16(r);
    l = *(unsigned short*)&lb;
}

__device__ __forceinline__ void gload16(const unsigned short* g, void* l) {
    __builtin_amdgcn_global_load_lds(
        (const __attribute__((address_space(1))) unsigned int*)g,
        (__attribute__((address_space(3))) unsigned int*)l, 16, 0, 0);
}

// ===========================================================================
// k8-interleaved operand layout:  Xp[s][r][j] = X[r][s*8+j]
// ===========================================================================

// --- 64x64 fp32 tile helpers, XOR-swizzled in 16B units ---
__device__ __forceinline__ void tile_load(const float* __restrict__ src, int ld,
                                          float (*tile)[64], int tid)
{
#pragma unroll
    for (int p = 0; p < 4; ++p) {
        const int f = p * 256 + tid;
        const int r = f >> 4, c4 = f & 15;
        const float4 v = *(const float4*)&src[(size_t)r * ld + c4 * 4];
        *(float4*)&tile[r][((c4 ^ (r & 7))) << 2] = v;
    }
}

__device__ __forceinline__ void tile_outA(float (*tile)[64],
                                          unsigned short* __restrict__ H,
                                          unsigned short* __restrict__ L,
                                          size_t Ms, size_t sg_base, size_t m_base, int tid)
{
#pragma unroll
    for (int p = 0; p < 2; ++p) {
        const int task = p * 256 + tid;
        const int s = task >> 6, mm = task & 63;
        const float4 x = *(const float4*)&tile[mm][(((s << 1)    ) ^ (mm & 7)) << 2];
        const float4 y = *(const float4*)&tile[mm][(((s << 1) | 1) ^ (mm & 7)) << 2];
        ushort4 ha, la, hb, lb;
        split2(x.x, ha.x, la.x); split2(x.y, ha.y, la.y);
        split2(x.z, ha.z, la.z); split2(x.w, ha.w, la.w);
        split2(y.x, hb.x, lb.x); split2(y.y, hb.y, lb.y);
        split2(y.z, hb.z, lb.z); split2(y.w, hb.w, lb.w);
        const size_t o = ((sg_base + s) * Ms + m_base + mm) * 8;
        *(ushort4*)&H[o] = ha; *(ushort4*)&H[o + 4] = hb;
        *(ushort4*)&L[o] = la; *(ushort4*)&L[o + 4] = lb;
    }
}

__device__ __forceinline__ void tile_outT(float (*tile)[64],
                                          unsigned short* __restrict__ H,
                                          unsigned short* __restrict__ L,
                                          size_t Ns, size_t sg_base, size_t n_base, int tid)
{
#pragma unroll
    for (int p = 0; p < 2; ++p) {
        const int task = p * 256 + tid;
        const int s2 = task >> 6, hh = task & 63;
        float v[8];
#pragma unroll
        for (int q = 0; q < 8; ++q) {
            const int r = s2 * 8 + q;
            v[q] = tile[r][((((hh >> 2)) ^ (r & 7)) << 2) + (hh & 3)];
        }
        ushort4 ha, la, hb, lb;
        split2(v[0], ha.x, la.x); split2(v[1], ha.y, la.y);
        split2(v[2], ha.z, la.z); split2(v[3], ha.w, la.w);
        split2(v[4], hb.x, lb.x); split2(v[5], hb.y, lb.y);
        split2(v[6], hb.z, lb.z); split2(v[7], hb.w, lb.w);
        const size_t o = ((sg_base + s2) * Ns + n_base + hh) * 8;
        *(ushort4*)&H[o] = ha; *(ushort4*)&H[o + 4] = hb;
        *(ushort4*)&L[o] = la; *(ushort4*)&L[o + 4] = lb;
    }
}

// ---------------------------------------------------------------------------
// split task executor (shared by mega and standalone): task id -> round-14 map
// ---------------------------------------------------------------------------
__device__ __forceinline__ void split_task(int x, int y, int z, float (*tile)[64], int tid,
    const float* enc, unsigned short* eAh, unsigned short* eAl,
    unsigned short* eTh, unsigned short* eTl,
    const float* dec, unsigned short* dH, unsigned short* dL,
    const float* Wa, unsigned short* wH, unsigned short* wL,
    const float* Ua, unsigned short* uH, unsigned short* uL)
{
    if (z < 16) {
        if (y < 8) {
            const int h0 = x * 64, t0 = y * 64;
            const size_t bo = (size_t)z * TE * HE;
            tile_load(enc + bo + (size_t)t0 * HE + h0, HE, tile, tid);
            __syncthreads();
            tile_outA(tile, eAh, eAl, (size_t)BB * TE, h0 >> 3, (size_t)z * TE + t0, tid);
            tile_outT(tile, eTh + bo, eTl + bo, HE, t0 >> 3, h0, tid);
        } else if (y == 8) {
            const int m0 = z * 64, h0 = x * 64;
            tile_load(dec + (size_t)m0 * HE + h0, HE, tile, tid);
            __syncthreads();
            tile_outA(tile, dH, dL, (size_t)BB * TD, h0 >> 3, m0, tid);
        }
        return;
    }
    const int yy = (y < 8) ? y : y - 8;
    const float* X = (y < 8) ? Wa : Ua;
    unsigned short* H = (y < 8) ? wH : uH;
    unsigned short* L = (y < 8) ? wL : uL;
    const int r0 = yy * 64, c0 = x * 64;
    tile_load(X + (size_t)r0 * HE + c0, HE, tile, tid);
    __syncthreads();
    tile_outT(tile, H, L, HE, r0 >> 3, c0, tid);
}

// ---------------------------------------------------------------------------
// 64x64 split-bf16 MFMA GEMM task (BK=32, 4 waves 2x2, LDS 2x16KB from `L`),
// counted vmcnt(4).
// ---------------------------------------------------------------------------
__device__ __forceinline__ void gemm64(char* L,
    const unsigned short* Ahi, const unsigned short* Alo,
    const unsigned short* Bhi, const unsigned short* Blo,
    float* C, int M, int N, int K, int row0, int col0, int emode, int tid)
{
    const int lane = tid & 63;
    const int wave = tid >> 6;
    const int wr = wave >> 1, wc = wave & 1;
    const int fr = lane & 15, fg = lane >> 4;

    f32x4 acc[2][2];
#pragma unroll
    for (int mi = 0; mi < 2; ++mi)
#pragma unroll
        for (int ni = 0; ni < 2; ++ni)
            acc[mi][ni] = (f32x4){0.f, 0.f, 0.f, 0.f};

    auto STAGE = [&](int buf, int k0) {
        const int sg = k0 >> 3;
        const int g = tid >> 6, idx = tid & 63;
        char* sb = L + buf * 16384;
        int mrow = row0 + idx; if (mrow >= M) mrow -= M;
        const size_t ao = ((size_t)(sg + g) * M + mrow) * 8;
        const size_t bo = ((size_t)(sg + g) * N + col0 + idx) * 8;
        gload16(Ahi + ao, sb + tid * 16);
        gload16(Alo + ao, sb + 4096 + tid * 16);
        gload16(Bhi + bo, sb + 8192 + tid * 16);
        gload16(Blo + bo, sb + 12288 + tid * 16);
    };

    STAGE(0, 0);
    int buf = 0;
    for (int k0 = 0; k0 < K; k0 += 32) {
        if (k0 + 32 < K) {
            STAGE(buf ^ 1, k0 + 32);
            asm volatile("s_waitcnt vmcnt(4)\n\ts_barrier" ::: "memory");
        } else {
            asm volatile("s_waitcnt vmcnt(0)\n\ts_barrier" ::: "memory");
        }
        char* sb = L + buf * 16384;
        bf16x8 ah[2], al[2], bh[2], bl[2];
#pragma unroll
        for (int mi = 0; mi < 2; ++mi) {
            const int off = (fg * 64 + wr * 32 + mi * 16 + fr) * 16;
            ah[mi] = *(const bf16x8*)(sb + off);
            al[mi] = *(const bf16x8*)(sb + 4096 + off);
        }
#pragma unroll
        for (int ni = 0; ni < 2; ++ni) {
            const int off = (fg * 64 + wc * 32 + ni * 16 + fr) * 16;
            bh[ni] = *(const bf16x8*)(sb + 8192 + off);
            bl[ni] = *(const bf16x8*)(sb + 12288 + off);
        }
#pragma unroll
        for (int mi = 0; mi < 2; ++mi)
#pragma unroll
            for (int ni = 0; ni < 2; ++ni) {
                acc[mi][ni] = __builtin_amdgcn_mfma_f32_16x16x32_bf16(ah[mi], bh[ni], acc[mi][ni], 0, 0, 0);
                acc[mi][ni] = __builtin_amdgcn_mfma_f32_16x16x32_bf16(ah[mi], bl[ni], acc[mi][ni], 0, 0, 0);
                acc[mi][ni] = __builtin_amdgcn_mfma_f32_16x16x32_bf16(al[mi], bh[ni], acc[mi][ni], 0, 0, 0);
            }
        asm volatile("s_barrier" ::: "memory");
        buf ^= 1;
    }

#pragma unroll
    for (int mi = 0; mi < 2; ++mi) {
        const int rbase = row0 + wr * 32 + mi * 16 + fg * 4;
#pragma unroll
        for (int ni = 0; ni < 2; ++ni) {
            const int col = col0 + wc * 32 + ni * 16 + fr;
#pragma unroll
            for (int r = 0; r < 4; ++r) {
                const int row = rbase + r;
                if (row < M) {
                    float val = acc[mi][ni][r];
                    if (emode) val = fexp2(val * PRESCALE);
                    C[(size_t)row * N + col] = val;
                }
            }
        }
    }
}

// ---------------------------------------------------------------------------
// scores task (identical math to round-14 scores_raw)
// ---------------------------------------------------------------------------
__device__ __forceinline__ void scores_task(float (*Ws_s)[64], float (*Uh_s)[64],
    const float* Vr_s, int tt0, int quar, int d0, int b,
    const float* Ew, const float* Eu, float* part, int tid)
{
    const int tg = tid & 7;
    const int dg = tid >> 3;
    const float* Wsg = Ew + (long long)b * TE * HE;
    const float* Uhg = Eu + ((long long)b * TD + d0) * HE;

    float acc[4] = {0.f, 0.f, 0.f, 0.f};
    const int wswz = tg & 7;
    const int uswz = dg & 7;
    const int hbase = quar * (HE / 4);

    for (int hc = hbase; hc < hbase + HE / 4; hc += 64) {
        __syncthreads();
#pragma unroll
        for (int k = 0; k < 2; ++k) {
            const int idx = tid + k * 256;
            const int r   = idx >> 4;
            const int c4  = idx & 15;
            const float4 wv = *(const float4*)&Wsg[(long long)(tt0 + r) * HE + hc + c4 * 4];
            *(float4*)&Ws_s[r][(c4 ^ ((r >> 2) & 7)) * 4] = wv;
            const float4 uv = *(const float4*)&Uhg[(long long)r * HE + hc + c4 * 4];
            *(float4*)&Uh_s[r][(c4 ^ (r & 7)) * 4] = uv;
        }
        __syncthreads();

#pragma unroll 4
        for (int hs = 0; hs < 64; hs += 4) {
            const int h4 = hs >> 2;
            const float4 vv = *(const float4*)&Vr_s[hc + hs];
            const float4 u  = *(const float4*)&Uh_s[dg][(h4 ^ uswz) * 4];
#pragma unroll
            for (int i = 0; i < 4; ++i) {
                const float4 w = *(const float4*)&Ws_s[tg * 4 + i][(h4 ^ wswz) * 4];
                acc[i] = fmaf(vv.x, frcp(fmaf(w.x, u.x, 1.f)), acc[i]);
                acc[i] = fmaf(vv.y, frcp(fmaf(w.y, u.y, 1.f)), acc[i]);
                acc[i] = fmaf(vv.z, frcp(fmaf(w.z, u.z, 1.f)), acc[i]);
                acc[i] = fmaf(vv.w, frcp(fmaf(w.w, u.w, 1.f)), acc[i]);
            }
        }
    }

    float* dst = part + (size_t)quar * (BB * TD * TE);
    float4 o; o.x = acc[0]; o.y = acc[1]; o.z = acc[2]; o.w = acc[3];
    *(float4*)&dst[((long long)b * TD + d0 + dg) * TE + tt0 + tg * 4] = o;
}

// ---------------------------------------------------------------------------
// softmax task (4 rows per task via waves), emits e + A-k8 bf16 hi/lo
// ---------------------------------------------------------------------------
__device__ __forceinline__ void softmax_task(long long row, const float* part,
    float* e, unsigned short* H, unsigned short* L, int tid)
{
    const int lane = tid & 63;

    float4 a = {0.f, 0.f, 0.f, 0.f}, c = {0.f, 0.f, 0.f, 0.f};
#pragma unroll
    for (int q = 0; q < 4; ++q) {
        const float* p = part + (size_t)q * (BB * TD * TE) + row * TE;
        const float4 aq = *(const float4*)&p[lane * 4];
        const float4 cq = *(const float4*)&p[lane * 4 + 256];
        a.x += aq.x; a.y += aq.y; a.z += aq.z; a.w += aq.w;
        c.x += cq.x; c.y += cq.y; c.z += cq.z; c.w += cq.w;
    }

    float m = fmaxf(fmaxf(fmaxf(a.x, a.y), fmaxf(a.z, a.w)),
                    fmaxf(fmaxf(c.x, c.y), fmaxf(c.z, c.w)));
#pragma unroll
    for (int off = 32; off; off >>= 1) m = fmaxf(m, __shfl_xor(m, off));

    a.x = __expf(a.x - m); a.y = __expf(a.y - m); a.z = __expf(a.z - m); a.w = __expf(a.w - m);
    c.x = __expf(c.x - m); c.y = __expf(c.y - m); c.z = __expf(c.z - m); c.w = __expf(c.w - m);

    float s = (a.x + a.y + a.z + a.w) + (c.x + c.y + c.z + c.w);
#pragma unroll
    for (int off = 32; off; off >>= 1) s += __shfl_xor(s, off);

    const float inv = __fdividef(1.f, s);
    a.x *= inv; a.y *= inv; a.z *= inv; a.w *= inv;
    c.x *= inv; c.y *= inv; c.z *= inv; c.w *= inv;
    float* pe = e + row * TE;
    *(float4*)&pe[lane * 4] = a;
    *(float4*)&pe[lane * 4 + 256] = c;

    const int b = (int)(row >> 6);
    const int d = (int)(row & 63);
    const size_t base = (size_t)b * (TD * TE);
    ushort4 h, l;
    {
        const int t0 = lane * 4;
        const size_t o = base + ((size_t)(t0 >> 3) * TD + d) * 8 + (t0 & 7);
        split2(a.x, h.x, l.x); split2(a.y, h.y, l.y);
        split2(a.z, h.z, l.z); split2(a.w, h.w, l.w);
        *(ushort4*)&H[o] = h;
        *(ushort4*)&L[o] = l;
    }
    {
        const int t0 = lane * 4 + 256;
        const size_t o = base + ((size_t)(t0 >> 3) * TD + d) * 8 + (t0 & 7);
        split2(c.x, h.x, l.x); split2(c.y, h.y, l.y);
        split2(c.z, h.z, l.z); split2(c.w, h.w, l.w);
        *(ushort4*)&H[o] = h;
        *(ushort4*)&L[o] = l;
    }
}

// ---------------------------------------------------------------------------
// MEGA: all five phases in one cooperative kernel, grid-strided tasks,
// grid.sync() between phases. LDS: 32 KB union.
// ---------------------------------------------------------------------------
__global__ __launch_bounds__(256)
void mega(const float* enc, const float* dec, const float* Wa, const float* Ua,
          const float* Va, float* out, char* w)
{
    __shared__ __align__(16) char L[32768];
    cg::grid_group grid = cg::this_grid();
    const int tid  = threadIdx.x;
    const int nblk = gridDim.x;

    float* Ew  = (float*)(w);
    float* Eu  = (float*)(w + 16777216);
    unsigned short* encAh = (unsigned short*)(w + 18874368);
    unsigned short* encAl = (unsigned short*)(w + 27262976);
    unsigned short* encTh = (unsigned short*)(w + 35651584);
    unsigned short* encTl = (unsigned short*)(w + 44040192);
    unsigned short* decAh = (unsigned short*)(w + 52428800);
    unsigned short* decAl = (unsigned short*)(w + 53477376);
    unsigned short* WaTh  = (unsigned short*)(w + 54525952);
    unsigned short* WaTl  = (unsigned short*)(w + 55050240);
    unsigned short* UaTh  = (unsigned short*)(w + 55574528);
    unsigned short* UaTl  = (unsigned short*)(w + 56098816);
    unsigned short* eh    = (unsigned short*)(w + 56623104);
    unsigned short* el    = (unsigned short*)(w + 57671680);
    float* part  = (float*)(w + 58720256);
    float* c_out = out;
    float* e_out = out + (size_t)BB * TD * HE;

    // ---- P0: conversions (2176 tasks) ----
    {
        float (*tile)[64] = (float(*)[64])L;
        for (int t = blockIdx.x; t < 2176; t += nblk) {
            __syncthreads();   // protect tile reuse across task iterations
            const int z = t >> 7, rem = t & 127;
            const int y = rem >> 3, x = rem & 7;
            split_task(x, y, z, tile, tid, enc, encAh, encAl, encTh, encTl,
                       dec, decAh, decAl, Wa, WaTh, WaTl, Ua, UaTh, UaTl);
        }
    }
    grid.sync();

    // ---- P1: Ws+Uh GEMM (1024 + 128 tasks, 64x64 tiles) ----
    for (int t = blockIdx.x; t < 1152; t += nblk) {
        if (t < 1024) {
            gemm64(L, encAh, encAl, WaTh, WaTl, Ew, BB * TE, HE, HE,
                   (t >> 3) * 64, (t & 7) * 64, 1, tid);
        } else {
            const int tt = t - 1024;
            gemm64(L, decAh, decAl, UaTh, UaTl, Eu, BB * TD, HE, HE,
                   (tt >> 3) * 64, (tt & 7) * 64, 1, tid);
        }
    }
    grid.sync();

    // ---- P2: scores (2048 tasks) ----
    {
        float (*Ws_s)[64] = (float(*)[64])L;
        float (*Uh_s)[64] = (float(*)[64])(L + 8192);
        float* Vr_s = (float*)(L + 16384);
        if (tid < 128) {
            const float4 v = *(const float4*)&Va[tid * 4];
            float4 o; o.x = -2.f * v.x; o.y = -2.f * v.y; o.z = -2.f * v.z; o.w = -2.f * v.w;
            *(float4*)&Vr_s[tid * 4] = o;
        }
        for (int t = blockIdx.x; t < 2048; t += nblk) {
            const int x = t & 15, y = (t >> 4) & 7, z = t >> 7;
            scores_task(Ws_s, Uh_s, Vr_s, x * 32, y & 3, (y >> 2) * 32, z,
                        Ew, Eu, part, tid);
        }
    }
    grid.sync();

    // ---- P3: softmax (256 tasks x 4 rows) ----
    for (int t = blockIdx.x; t < 256; t += nblk) {
        const long long row = (long long)t * 4 + (tid >> 6);
        softmax_task(row, part, e_out, eh, el, tid);
    }
    grid.sync();

    // ---- P4: context GEMM (128 tasks, 64x64 tiles) ----
    for (int t = blockIdx.x; t < 128; t += nblk) {
        const int b = t >> 3, ct = t & 7;
        gemm64(L, eh + (size_t)b * TD * TE, el + (size_t)b * TD * TE,
               encTh + (size_t)b * TE * HE, encTl + (size_t)b * TE * HE,
               c_out + (size_t)b * TD * HE, TD, HE, TE, 0, ct * 64, 0, tid);
    }
}

// ===========================================================================
// Fallback standalone kernels (round-14 path, proven 90.6 us)
// ===========================================================================
__global__ __launch_bounds__(256)
void split_all(const float* __restrict__ enc,
               unsigned short* __restrict__ eAh, unsigned short* __restrict__ eAl,
               unsigned short* __restrict__ eTh, unsigned short* __restrict__ eTl,
               const float* __restrict__ dec,
               unsigned short* __restrict__ dH, unsigned short* __restrict__ dL,
               const float* __restrict__ Wa,
               unsigned short* __restrict__ wH, unsigned short* __restrict__ wL,
               const float* __restrict__ Ua,
               unsigned short* __restrict__ uH, unsigned short* __restrict__ uL)
{
    __shared__ float tile[64][64];
    split_task(blockIdx.x, blockIdx.y, blockIdx.z, tile, threadIdx.x,
               enc, eAh, eAl, eTh, eTl, dec, dH, dL, Wa, wH, wL, Ua, uH, uL);
}

__global__ __launch_bounds__(256)
void gemm_ws_uh(const unsigned short* __restrict__ eAh, const unsigned short* __restrict__ eAl,
                const unsigned short* __restrict__ wBh, const unsigned short* __restrict__ wBl,
                float* __restrict__ Ew,
                const unsigned short* __restrict__ dAh, const unsigned short* __restrict__ dAl,
                const unsigned short* __restrict__ uBh, const unsigned short* __restrict__ uBl,
                float* __restrict__ Eu)
{
    __shared__ __align__(16) char L[32768];
    const int t = blockIdx.y * 8 + blockIdx.x;
    if (t < 1024)
        gemm64(L, eAh, eAl, wBh, wBl, Ew, BB * TE, HE, HE,
               (t >> 3) * 64, (t & 7) * 64, 1, threadIdx.x);
    else {
        const int tt = t - 1024;
        gemm64(L, dAh, dAl, uBh, uBl, Eu, BB * TD, HE, HE,
               (tt >> 3) * 64, (tt & 7) * 64, 1, threadIdx.x);
    }
}

__global__ __launch_bounds__(256)
void gemm_ctx(const unsigned short* __restrict__ eh, const unsigned short* __restrict__ el,
              const unsigned short* __restrict__ eTh, const unsigned short* __restrict__ eTl,
              float* __restrict__ C)
{
    __shared__ __align__(16) char L[32768];
    const int b = blockIdx.z, ct = blockIdx.x;
    gemm64(L, eh + (size_t)b * TD * TE, el + (size_t)b * TD * TE,
           eTh + (size_t)b * TE * HE, eTl + (size_t)b * TE * HE,
           C + (size_t)b * TD * HE, TD, HE, TE, 0, ct * 64, 0, threadIdx.x);
}

__global__ __launch_bounds__(256)
void scores_raw(const float* __restrict__ Ew, const float* __restrict__ Eu,
                const float* __restrict__ V, float* __restrict__ part)
{
    __shared__ float Ws_s[32][64];
    __shared__ float Uh_s[32][64];
    __shared__ float Vr_s[HE];
    const int tid = threadIdx.x;
    if (tid < 128) {
        const float4 v = *(const float4*)&V[tid * 4];
        float4 o; o.x = -2.f * v.x; o.y = -2.f * v.y; o.z = -2.f * v.z; o.w = -2.f * v.w;
        *(float4*)&Vr_s[tid * 4] = o;
    }
    scores_task(Ws_s, Uh_s, Vr_s, blockIdx.x * 32, blockIdx.y & 3,
                (blockIdx.y >> 2) * 32, blockIdx.z, Ew, Eu, part, tid);
}

__global__ __launch_bounds__(256)
void softmax_rows(const float* __restrict__ part, float* __restrict__ e,
                  unsigned short* __restrict__ H, unsigned short* __restrict__ L)
{
    const long long row = (long long)blockIdx.x * 4 + (threadIdx.x >> 6);
    softmax_task(row, part, e, H, L, threadIdx.x);
}

// fp32 fallback GEMM (tiny-ws path)
__global__ __launch_bounds__(256)
void gemm_f32(const float* __restrict__ A, const float* __restrict__ Bm,
              float* __restrict__ C, int M, int N, int K,
              long long sAb, long long sBb, long long sCb, float scale, int emode)
{
    __shared__ float As[16][68];
    __shared__ float Bs[16][68];
    const int tid = threadIdx.x;
    const int tx = tid & 15, ty = tid >> 4;
    const int row0 = blockIdx.y * 64, col0 = blockIdx.x * 64;
    A += (long long)blockIdx.z * sAb; Bm += (long long)blockIdx.z * sBb;
    C += (long long)blockIdx.z * sCb;
    float acc[4][4] = {};
    for (int k0 = 0; k0 < K; k0 += 16) {
        {
            const int r = tid >> 2, c = (tid & 3) * 4;
            const float4 av = *(const float4*)&A[(long long)(row0 + r) * K + k0 + c];
            As[c + 0][r] = av.x; As[c + 1][r] = av.y;
            As[c + 2][r] = av.z; As[c + 3][r] = av.w;
        }
        {
            const int r = tid >> 4, c = (tid & 15) * 4;
            *(float4*)&Bs[r][c] = *(const float4*)&Bm[(long long)(k0 + r) * N + col0 + c];
        }
        __syncthreads();
#pragma unroll
        for (int kk = 0; kk < 16; ++kk) {
            const float4 a = *(const float4*)&As[kk][ty * 4];
            const float4 b = *(const float4*)&Bs[kk][tx * 4];
            acc[0][0] += a.x * b.x; acc[0][1] += a.x * b.y; acc[0][2] += a.x * b.z; acc[0][3] += a.x * b.w;
            acc[1][0] += a.y * b.x; acc[1][1] += a.y * b.y; acc[1][2] += a.y * b.z; acc[1][3] += a.y * b.w;
            acc[2][0] += a.z * b.x; acc[2][1] += a.z * b.y; acc[2][2] += a.z * b.z; acc[2][3] += a.z * b.w;
            acc[3][0] += a.w * b.x; acc[3][1] += a.w * b.y; acc[3][2] += a.w * b.z; acc[3][3] += a.w * b.w;
        }
        __syncthreads();
    }
#pragma unroll
    for (int i = 0; i < 4; ++i) {
        float4 o;
        o.x = acc[i][0] * scale; o.y = acc[i][1] * scale;
        o.z = acc[i][2] * scale; o.w = acc[i][3] * scale;
        if (emode) { o.x = fexp2(o.x); o.y = fexp2(o.y); o.z = fexp2(o.z); o.w = fexp2(o.w); }
        *(float4*)&C[(long long)(row0 + ty * 4 + i) * N + col0 + tx * 4] = o;
    }
}

// ---------------------------------------------------------------------------
extern "C" void kernel_launch(void* const* d_in, const int* in_sizes, int n_in,
                              void* d_out, int out_size, void* d_ws, size_t ws_size,
                              hipStream_t stream)
{
    const float* enc = (const float*)d_in[0];
    const float* dec = (const float*)d_in[1];
    const float* Wa  = (const float*)d_in[2];
    const float* Ua  = (const float*)d_in[3];
    const float* Va  = (const float*)d_in[4];

    float* out   = (float*)d_out;
    float* c_out = out;
    float* e_out = out + (size_t)BB * TD * HE;

    char* w = (char*)d_ws;
    float* Ew  = (float*)(w);
    float* Eu  = (float*)(w + 16777216);
    unsigned short* encAh = (unsigned short*)(w + 18874368);
    unsigned short* encAl = (unsigned short*)(w + 27262976);
    unsigned short* encTh = (unsigned short*)(w + 35651584);
    unsigned short* encTl = (unsigned short*)(w + 44040192);
    unsigned short* decAh = (unsigned short*)(w + 52428800);
    unsigned short* decAl = (unsigned short*)(w + 53477376);
    unsigned short* WaTh  = (unsigned short*)(w + 54525952);
    unsigned short* WaTl  = (unsigned short*)(w + 55050240);
    unsigned short* UaTh  = (unsigned short*)(w + 55574528);
    unsigned short* UaTl  = (unsigned short*)(w + 56098816);
    unsigned short* eh    = (unsigned short*)(w + 56623104);
    unsigned short* el    = (unsigned short*)(w + 57671680);
    float* part = (float*)(w + 58720256);
    const size_t REQUIRED = 67108864;

    dim3 blk(256);

    int coop = 0, dev = 0;
    hipGetDevice(&dev);
    hipDeviceGetAttribute(&coop, hipDeviceAttributeCooperativeLaunch, dev);
    int maxblk = 0;
    hipOccupancyMaxActiveBlocksPerMultiprocessor(&maxblk, mega, 256, (size_t)0);

    if (ws_size >= REQUIRED && coop && maxblk >= 1) {
        int G = maxblk * 256;
        if (G > 2048) G = 2048;
        void* args[] = {(void*)&enc, (void*)&dec, (void*)&Wa, (void*)&Ua,
                        (void*)&Va, (void*)&out, (void*)&w};
        hipLaunchCooperativeKernel(mega, dim3(G), blk, args, 0u, stream);
    } else if (ws_size >= REQUIRED) {
        split_all<<<dim3(8, 16, 17), blk, 0, stream>>>(
            enc, encAh, encAl, encTh, encTl,
            dec, decAh, decAl, Wa, WaTh, WaTl, Ua, UaTh, UaTl);
        gemm_ws_uh<<<dim3(8, 144, 1), blk, 0, stream>>>(
            encAh, encAl, WaTh, WaTl, Ew, decAh, decAl, UaTh, UaTl, Eu);
        scores_raw<<<dim3(TE / 32, (TD / 32) * 4, BB), blk, 0, stream>>>(Ew, Eu, Va, part);
        softmax_rows<<<dim3(BB * TD / 4), blk, 0, stream>>>(part, e_out, eh, el);
        gemm_ctx<<<dim3(8, 1, BB), blk, 0, stream>>>(eh, el, encTh, encTl, c_out);
    } else {
        float* pf = (float*)(w + 18874368);
        gemm_f32<<<dim3(HE / 64, (BB * TE) / 64, 1), blk, 0, stream>>>(
            enc, Wa, Ew, BB * TE, HE, HE, 0, 0, 0, PRESCALE, 1);
        gemm_f32<<<dim3(HE / 64, (BB * TD) / 64, 1), blk, 0, stream>>>(
            dec, Ua, Eu, BB * TD, HE, HE, 0, 0, 0, PRESCALE, 1);
        scores_raw<<<dim3(TE / 32, (TD / 32) * 4, BB), blk, 0, stream>>>(Ew, Eu, Va, pf);
        softmax_rows<<<dim3(BB * TD / 4), blk, 0, stream>>>(pf, e_out, nullptr, nullptr);
        gemm_f32<<<dim3(HE / 64, TD / 64, BB), blk, 0, stream>>>(
            e_out, enc, c_out, TD, HE, TE,
            (long long)TD * TE, (long long)TE * HE, (long long)TD * HE, 1.0f, 0);
    }
}

// Round 17
// 87.364 us; speedup vs baseline: 2.8346x; 2.8346x over previous
//
#include <hip/hip_runtime.h>
#include <hip/hip_bf16.h>

#define BB 16
#define TE 512
#define TD 64
#define HE 512

// 2*log2(e): folded into Ws/Uh GEMM epilogue (with exp2) so the scores inner
// loop needs no exp at all: tanh term via 1/(Ew*Eu+1).
#define PRESCALE 2.8853900817779268f

typedef __attribute__((ext_vector_type(8))) short bf16x8;
typedef __attribute__((ext_vector_type(4))) float f32x4;

__device__ __forceinline__ float fexp2(float x) {
#if __has_builtin(__builtin_amdgcn_exp2f)
    return __builtin_amdgcn_exp2f(x);
#else
    return exp2f(x);
#endif
}
__device__ __forceinline__ float frcp(float x) {
#if __has_builtin(__builtin_amdgcn_rcpf)
    return __builtin_amdgcn_rcpf(x);
#else
    return __fdividef(1.f, x);
#endif
}

// split fp32 -> bf16 hi + bf16 lo (x ~= hi + lo, ~2^-17 relative)
__device__ __forceinline__ void split2(float x, unsigned short& h, unsigned short& l) {
    __hip_bfloat16 hb = __float2bfloat16(x);
    h = *(unsigned short*)&hb;
    float r = x - __bfloat162float(hb);
    __hip_bfloat16 lb = __float2bfloat16(r);
    l = *(unsigned short*)&lb;
}

__device__ __forceinline__ void gload16(const unsigned short* g, void* l) {
    __builtin_amdgcn_global_load_lds(
        (const __attribute__((address_space(1))) unsigned int*)g,
        (__attribute__((address_space(3))) unsigned int*)l, 16, 0, 0);
}

// ===========================================================================
// k8-interleaved operand layout:  Xp[s][r][j] = X[r][s*8+j]
// ===========================================================================

// --- 64x64 fp32 tile helpers, XOR-swizzled in 16B units ---
__device__ __forceinline__ void tile_load(const float* __restrict__ src, int ld,
                                          float (*tile)[64], int tid)
{
#pragma unroll
    for (int p = 0; p < 4; ++p) {
        const int f = p * 256 + tid;
        const int r = f >> 4, c4 = f & 15;
        const float4 v = *(const float4*)&src[(size_t)r * ld + c4 * 4];
        *(float4*)&tile[r][((c4 ^ (r & 7))) << 2] = v;
    }
}

__device__ __forceinline__ void tile_outA(float (*tile)[64],
                                          unsigned short* __restrict__ H,
                                          unsigned short* __restrict__ L,
                                          size_t Ms, size_t sg_base, size_t m_base, int tid)
{
#pragma unroll
    for (int p = 0; p < 2; ++p) {
        const int task = p * 256 + tid;
        const int s = task >> 6, mm = task & 63;
        const float4 x = *(const float4*)&tile[mm][(((s << 1)    ) ^ (mm & 7)) << 2];
        const float4 y = *(const float4*)&tile[mm][(((s << 1) | 1) ^ (mm & 7)) << 2];
        ushort4 ha, la, hb, lb;
        split2(x.x, ha.x, la.x); split2(x.y, ha.y, la.y);
        split2(x.z, ha.z, la.z); split2(x.w, ha.w, la.w);
        split2(y.x, hb.x, lb.x); split2(y.y, hb.y, lb.y);
        split2(y.z, hb.z, lb.z); split2(y.w, hb.w, lb.w);
        const size_t o = ((sg_base + s) * Ms + m_base + mm) * 8;
        *(ushort4*)&H[o] = ha; *(ushort4*)&H[o + 4] = hb;
        *(ushort4*)&L[o] = la; *(ushort4*)&L[o + 4] = lb;
    }
}

__device__ __forceinline__ void tile_outT(float (*tile)[64],
                                          unsigned short* __restrict__ H,
                                          unsigned short* __restrict__ L,
                                          size_t Ns, size_t sg_base, size_t n_base, int tid)
{
#pragma unroll
    for (int p = 0; p < 2; ++p) {
        const int task = p * 256 + tid;
        const int s2 = task >> 6, hh = task & 63;
        float v[8];
#pragma unroll
        for (int q = 0; q < 8; ++q) {
            const int r = s2 * 8 + q;
            v[q] = tile[r][((((hh >> 2)) ^ (r & 7)) << 2) + (hh & 3)];
        }
        ushort4 ha, la, hb, lb;
        split2(v[0], ha.x, la.x); split2(v[1], ha.y, la.y);
        split2(v[2], ha.z, la.z); split2(v[3], ha.w, la.w);
        split2(v[4], hb.x, lb.x); split2(v[5], hb.y, lb.y);
        split2(v[6], hb.z, lb.z); split2(v[7], hb.w, lb.w);
        const size_t o = ((sg_base + s2) * Ns + n_base + hh) * 8;
        *(ushort4*)&H[o] = ha; *(ushort4*)&H[o + 4] = hb;
        *(ushort4*)&L[o] = la; *(ushort4*)&L[o + 4] = lb;
    }
}

// ---------------------------------------------------------------------------
// split_all: ALL conversions in one launch. grid (8, 16, 17)  [proven r14]
// ---------------------------------------------------------------------------
__global__ __launch_bounds__(256)
void split_all(const float* __restrict__ enc,
               unsigned short* __restrict__ eAh, unsigned short* __restrict__ eAl,
               unsigned short* __restrict__ eTh, unsigned short* __restrict__ eTl,
               const float* __restrict__ dec,
               unsigned short* __restrict__ dH, unsigned short* __restrict__ dL,
               const float* __restrict__ Wa,
               unsigned short* __restrict__ wH, unsigned short* __restrict__ wL,
               const float* __restrict__ Ua,
               unsigned short* __restrict__ uH, unsigned short* __restrict__ uL)
{
    __shared__ float tile[64][64];
    const int tid = threadIdx.x;
    const int x = blockIdx.x, y = blockIdx.y, z = blockIdx.z;

    if (z < 16) {
        if (y < 8) {
            const int h0 = x * 64, t0 = y * 64;
            const size_t bo = (size_t)z * TE * HE;
            tile_load(enc + bo + (size_t)t0 * HE + h0, HE, tile, tid);
            __syncthreads();
            tile_outA(tile, eAh, eAl, (size_t)BB * TE, h0 >> 3, (size_t)z * TE + t0, tid);
            tile_outT(tile, eTh + bo, eTl + bo, HE, t0 >> 3, h0, tid);
        } else if (y == 8) {
            const int m0 = z * 64, h0 = x * 64;
            tile_load(dec + (size_t)m0 * HE + h0, HE, tile, tid);
            __syncthreads();
            tile_outA(tile, dH, dL, (size_t)BB * TD, h0 >> 3, m0, tid);
        }
        return;
    }
    const int yy = (y < 8) ? y : y - 8;
    const float* X = (y < 8) ? Wa : Ua;
    unsigned short* H = (y < 8) ? wH : uH;
    unsigned short* L = (y < 8) ? wL : uL;
    const int r0 = yy * 64, c0 = x * 64;
    tile_load(X + (size_t)r0 * HE + c0, HE, tile, tid);
    __syncthreads();
    tile_outT(tile, H, L, HE, r0 >> 3, c0, tid);
}

// ---------------------------------------------------------------------------
// Merged Ws+Uh GEMM [proven r13 128x128 BK=32 counted-vmcnt] + XCD swizzle:
// work = (hw%8)*36 + hw/8 over 288 blocks -> the 4 col-tiles of one A
// row-tile land on one XCD (A row-tile = 256 KB, L2-resident).
// ---------------------------------------------------------------------------
__global__ __launch_bounds__(256)
void gemm_ws_uh(const unsigned short* __restrict__ eAh, const unsigned short* __restrict__ eAl,
                const unsigned short* __restrict__ wBh, const unsigned short* __restrict__ wBl,
                float* __restrict__ Ew,
                const unsigned short* __restrict__ dAh, const unsigned short* __restrict__ dAl,
                const unsigned short* __restrict__ uBh, const unsigned short* __restrict__ uBl,
                float* __restrict__ Eu)
{
    __shared__ char smem[2][32768];

    const int tid  = threadIdx.x;
    const int lane = tid & 63;
    const int wave = tid >> 6;
    const int wr = wave >> 1, wc = wave & 1;
    const int fr = lane & 15, fg = lane >> 4;

    // XCD swizzle: hw flat id -> work id (288 = 8 * 36, bijective)
    const int hw = blockIdx.y * 4 + blockIdx.x;
    const int f  = (hw & 7) * 36 + (hw >> 3);
    const int bx = f & 3, by = f >> 2;

    const unsigned short *Ahi, *Alo, *Bhi, *Blo;
    float* C;
    int M, row0;
    if (by < 64) {
        Ahi = eAh; Alo = eAl; Bhi = wBh; Blo = wBl; C = Ew;
        M = BB * TE; row0 = by * 128;
    } else {
        Ahi = dAh; Alo = dAl; Bhi = uBh; Blo = uBl; C = Eu;
        M = BB * TD; row0 = (by - 64) * 128;
    }
    const int N = HE, K = HE;
    const int col0 = bx * 128;

    f32x4 acc[4][4];
#pragma unroll
    for (int mi = 0; mi < 4; ++mi)
#pragma unroll
        for (int ni = 0; ni < 4; ++ni)
            acc[mi][ni] = (f32x4){0.f, 0.f, 0.f, 0.f};

    auto STAGE = [&](int buf, int k0) {
#pragma unroll
        for (int c = 0; c < 2; ++c) {
            const int bi  = (c * 4 + wave) * 64 + lane;
            const int g   = bi >> 7;
            const int idx = bi & 127;
            int mrow = row0 + idx; if (mrow >= M) mrow -= M;
            const int ncol = col0 + idx;
            const size_t ao = ((size_t)((k0 >> 3) + g) * M + mrow) * 8;
            const size_t bo = ((size_t)((k0 >> 3) + g) * N + ncol) * 8;
            const int lb = (c * 4 + wave) * 1024;
            gload16(Ahi + ao, smem[buf] + lb);
            gload16(Alo + ao, smem[buf] + 8192 + lb);
            gload16(Bhi + bo, smem[buf] + 16384 + lb);
            gload16(Blo + bo, smem[buf] + 24576 + lb);
        }
    };

    STAGE(0, 0);

    int buf = 0;
    for (int k0 = 0; k0 < K; k0 += 32) {
        if (k0 + 32 < K) {
            STAGE(buf ^ 1, k0 + 32);
            asm volatile("s_waitcnt vmcnt(8)\n\ts_barrier" ::: "memory");
        } else {
            asm volatile("s_waitcnt vmcnt(0)\n\ts_barrier" ::: "memory");
        }

        const int gb = fg << 7;
        bf16x8 ah[4], al[4], bh[4], bl[4];
#pragma unroll
        for (int mi = 0; mi < 4; ++mi) {
            const int off = (gb + wr * 64 + mi * 16 + fr) * 16;
            ah[mi] = *(const bf16x8*)(smem[buf] + off);
            al[mi] = *(const bf16x8*)(smem[buf] + 8192 + off);
        }
#pragma unroll
        for (int ni = 0; ni < 4; ++ni) {
            const int off = (gb + wc * 64 + ni * 16 + fr) * 16;
            bh[ni] = *(const bf16x8*)(smem[buf] + 16384 + off);
            bl[ni] = *(const bf16x8*)(smem[buf] + 24576 + off);
        }
#pragma unroll
        for (int mi = 0; mi < 4; ++mi)
#pragma unroll
            for (int ni = 0; ni < 4; ++ni) {
                acc[mi][ni] = __builtin_amdgcn_mfma_f32_16x16x32_bf16(ah[mi], bh[ni], acc[mi][ni], 0, 0, 0);
                acc[mi][ni] = __builtin_amdgcn_mfma_f32_16x16x32_bf16(ah[mi], bl[ni], acc[mi][ni], 0, 0, 0);
                acc[mi][ni] = __builtin_amdgcn_mfma_f32_16x16x32_bf16(al[mi], bh[ni], acc[mi][ni], 0, 0, 0);
            }
        asm volatile("s_barrier" ::: "memory");
        buf ^= 1;
    }

#pragma unroll
    for (int mi = 0; mi < 4; ++mi) {
        const int rbase = row0 + wr * 64 + mi * 16 + fg * 4;
#pragma unroll
        for (int ni = 0; ni < 4; ++ni) {
            const int col = col0 + wc * 64 + ni * 16 + fr;
#pragma unroll
            for (int r = 0; r < 4; ++r) {
                const int row = rbase + r;
                if (row < M) C[(size_t)row * N + col] = fexp2(acc[mi][ni][r] * PRESCALE);
            }
        }
    }
}

// ---------------------------------------------------------------------------
// Batched context GEMM [proven r13]: c[b] = e[b] @ enc[b], 128x128 tile
// ---------------------------------------------------------------------------
__global__ __launch_bounds__(256)
void gemm_mfma3(const unsigned short* __restrict__ Ahi, const unsigned short* __restrict__ Alo,
                const unsigned short* __restrict__ Bhi, const unsigned short* __restrict__ Blo,
                float* __restrict__ C, int M, int N, int K,
                long long sA, long long sB, long long sC)
{
    __shared__ char smem[2][32768];

    const int tid  = threadIdx.x;
    const int lane = tid & 63;
    const int wave = tid >> 6;
    const int wr = wave >> 1, wc = wave & 1;
    const int fr = lane & 15, fg = lane >> 4;
    const int row0 = blockIdx.y * 128;
    const int col0 = blockIdx.x * 128;

    Ahi += (size_t)blockIdx.z * sA; Alo += (size_t)blockIdx.z * sA;
    Bhi += (size_t)blockIdx.z * sB; Blo += (size_t)blockIdx.z * sB;
    C   += (size_t)blockIdx.z * sC;

    f32x4 acc[4][4];
#pragma unroll
    for (int mi = 0; mi < 4; ++mi)
#pragma unroll
        for (int ni = 0; ni < 4; ++ni)
            acc[mi][ni] = (f32x4){0.f, 0.f, 0.f, 0.f};

    auto STAGE = [&](int buf, int k0) {
#pragma unroll
        for (int c = 0; c < 2; ++c) {
            const int bi  = (c * 4 + wave) * 64 + lane;
            const int g   = bi >> 7;
            const int idx = bi & 127;
            int mrow = row0 + idx; if (mrow >= M) mrow -= M;
            const int ncol = col0 + idx;
            const size_t ao = ((size_t)((k0 >> 3) + g) * M + mrow) * 8;
            const size_t bo = ((size_t)((k0 >> 3) + g) * N + ncol) * 8;
            const int lb = (c * 4 + wave) * 1024;
            gload16(Ahi + ao, smem[buf] + lb);
            gload16(Alo + ao, smem[buf] + 8192 + lb);
            gload16(Bhi + bo, smem[buf] + 16384 + lb);
            gload16(Blo + bo, smem[buf] + 24576 + lb);
        }
    };

    STAGE(0, 0);

    int buf = 0;
    for (int k0 = 0; k0 < K; k0 += 32) {
        if (k0 + 32 < K) {
            STAGE(buf ^ 1, k0 + 32);
            asm volatile("s_waitcnt vmcnt(8)\n\ts_barrier" ::: "memory");
        } else {
            asm volatile("s_waitcnt vmcnt(0)\n\ts_barrier" ::: "memory");
        }

        const int gb = fg << 7;
        bf16x8 ah[4], al[4], bh[4], bl[4];
#pragma unroll
        for (int mi = 0; mi < 4; ++mi) {
            const int off = (gb + wr * 64 + mi * 16 + fr) * 16;
            ah[mi] = *(const bf16x8*)(smem[buf] + off);
            al[mi] = *(const bf16x8*)(smem[buf] + 8192 + off);
        }
#pragma unroll
        for (int ni = 0; ni < 4; ++ni) {
            const int off = (gb + wc * 64 + ni * 16 + fr) * 16;
            bh[ni] = *(const bf16x8*)(smem[buf] + 16384 + off);
            bl[ni] = *(const bf16x8*)(smem[buf] + 24576 + off);
        }
#pragma unroll
        for (int mi = 0; mi < 4; ++mi)
#pragma unroll
            for (int ni = 0; ni < 4; ++ni) {
                acc[mi][ni] = __builtin_amdgcn_mfma_f32_16x16x32_bf16(ah[mi], bh[ni], acc[mi][ni], 0, 0, 0);
                acc[mi][ni] = __builtin_amdgcn_mfma_f32_16x16x32_bf16(ah[mi], bl[ni], acc[mi][ni], 0, 0, 0);
                acc[mi][ni] = __builtin_amdgcn_mfma_f32_16x16x32_bf16(al[mi], bh[ni], acc[mi][ni], 0, 0, 0);
            }
        asm volatile("s_barrier" ::: "memory");
        buf ^= 1;
    }

#pragma unroll
    for (int mi = 0; mi < 4; ++mi) {
        const int rbase = row0 + wr * 64 + mi * 16 + fg * 4;
#pragma unroll
        for (int ni = 0; ni < 4; ++ni) {
            const int col = col0 + wc * 64 + ni * 16 + fr;
#pragma unroll
            for (int r = 0; r < 4; ++r) {
                const int row = rbase + r;
                if (row < M) C[(size_t)row * N + col] = acc[mi][ni][r];
            }
        }
    }
}

// ---------------------------------------------------------------------------
// Fallback fp32 GEMM (used if ws_size is too small)
// ---------------------------------------------------------------------------
__global__ __launch_bounds__(256)
void gemm_f32(const float* __restrict__ A, const float* __restrict__ Bm,
              float* __restrict__ C, int M, int N, int K,
              long long sAb, long long sBb, long long sCb, float scale, int emode)
{
    __shared__ float As[16][68];
    __shared__ float Bs[16][68];
    const int tid = threadIdx.x;
    const int tx = tid & 15, ty = tid >> 4;
    const int row0 = blockIdx.y * 64, col0 = blockIdx.x * 64;
    A += (long long)blockIdx.z * sAb; Bm += (long long)blockIdx.z * sBb;
    C += (long long)blockIdx.z * sCb;
    float acc[4][4] = {};
    for (int k0 = 0; k0 < K; k0 += 16) {
        {
            const int r = tid >> 2, c = (tid & 3) * 4;
            const float4 av = *(const float4*)&A[(long long)(row0 + r) * K + k0 + c];
            As[c + 0][r] = av.x; As[c + 1][r] = av.y;
            As[c + 2][r] = av.z; As[c + 3][r] = av.w;
        }
        {
            const int r = tid >> 4, c = (tid & 15) * 4;
            *(float4*)&Bs[r][c] = *(const float4*)&Bm[(long long)(k0 + r) * N + col0 + c];
        }
        __syncthreads();
#pragma unroll
        for (int kk = 0; kk < 16; ++kk) {
            const float4 a = *(const float4*)&As[kk][ty * 4];
            const float4 b = *(const float4*)&Bs[kk][tx * 4];
            acc[0][0] += a.x * b.x; acc[0][1] += a.x * b.y; acc[0][2] += a.x * b.z; acc[0][3] += a.x * b.w;
            acc[1][0] += a.y * b.x; acc[1][1] += a.y * b.y; acc[1][2] += a.y * b.z; acc[1][3] += a.y * b.w;
            acc[2][0] += a.z * b.x; acc[2][1] += a.z * b.y; acc[2][2] += a.z * b.z; acc[2][3] += a.z * b.w;
            acc[3][0] += a.w * b.x; acc[3][1] += a.w * b.y; acc[3][2] += a.w * b.z; acc[3][3] += a.w * b.w;
        }
        __syncthreads();
    }
#pragma unroll
    for (int i = 0; i < 4; ++i) {
        float4 o;
        o.x = acc[i][0] * scale; o.y = acc[i][1] * scale;
        o.z = acc[i][2] * scale; o.w = acc[i][3] * scale;
        if (emode) { o.x = fexp2(o.x); o.y = fexp2(o.y); o.z = fexp2(o.z); o.w = fexp2(o.w); }
        *(float4*)&C[(long long)(row0 + ty * 4 + i) * N + col0 + tx * 4] = o;
    }
}

// ---------------------------------------------------------------------------
// Raw score PARTIALS over an h-quarter [proven 8 blk/CU structure] + XCD
// swizzle: work = (hw%8)*256 + hw/8 over 2048 blocks -> the 8 blocks sharing
// one Ws 64KB tile (same b, t-tile; varying quar/d-tile) land on one XCD.
// ---------------------------------------------------------------------------
__global__ __launch_bounds__(256)
void scores_raw(const float* __restrict__ Ew, const float* __restrict__ Eu,
                const float* __restrict__ V, float* __restrict__ part)
{
    __shared__ float Ws_s[32][64];   // [t][h-chunk], col4 ^= (row>>2)&7
    __shared__ float Uh_s[32][64];   // [d][h-chunk], col4 ^= row&7
    __shared__ float Vr_s[HE];       // -2*V

    const int tid = threadIdx.x;
    const int tg  = tid & 7;     // t-group: t = tt0 + tg*4 + i
    const int dg  = tid >> 3;    // d = d0 + dg   (0..31)

    // XCD swizzle (2048 = 8 * 256, bijective): w = (hw&7)*256 + hw>>3
    const int hw = (blockIdx.z * 8 + blockIdx.y) * 16 + blockIdx.x;
    const int w_ = (hw & 7) * 256 + (hw >> 3);
    const int yy = w_ & 7;            // quar | d-tile
    const int zx = w_ >> 3;           // b*16 + t-tile
    const int tt0  = (zx & 15) * 32;
    const int quar = yy & 3;
    const int d0   = (yy >> 2) * 32;
    const int b    = zx >> 4;

    const float* Wsg = Ew + (long long)b * TE * HE;
    const float* Uhg = Eu + ((long long)b * TD + d0) * HE;

    if (tid < 128) {
        const float4 v = *(const float4*)&V[tid * 4];
        float4 o; o.x = -2.f * v.x; o.y = -2.f * v.y; o.z = -2.f * v.z; o.w = -2.f * v.w;
        *(float4*)&Vr_s[tid * 4] = o;
    }

    float acc[4] = {0.f, 0.f, 0.f, 0.f};
    const int wswz = tg & 7;
    const int uswz = dg & 7;
    const int hbase = quar * (HE / 4);

    for (int hc = hbase; hc < hbase + HE / 4; hc += 64) {
        __syncthreads();
#pragma unroll
        for (int k = 0; k < 2; ++k) {
            const int idx = tid + k * 256;
            const int r   = idx >> 4;
            const int c4  = idx & 15;
            const float4 wv = *(const float4*)&Wsg[(long long)(tt0 + r) * HE + hc + c4 * 4];
            *(float4*)&Ws_s[r][(c4 ^ ((r >> 2) & 7)) * 4] = wv;
            const float4 uv = *(const float4*)&Uhg[(long long)r * HE + hc + c4 * 4];
            *(float4*)&Uh_s[r][(c4 ^ (r & 7)) * 4] = uv;
        }
        __syncthreads();

#pragma unroll 4
        for (int hs = 0; hs < 64; hs += 4) {
            const int h4 = hs >> 2;
            const float4 vv = *(const float4*)&Vr_s[hc + hs];
            const float4 u  = *(const float4*)&Uh_s[dg][(h4 ^ uswz) * 4];
#pragma unroll
            for (int i = 0; i < 4; ++i) {
                const float4 w = *(const float4*)&Ws_s[tg * 4 + i][(h4 ^ wswz) * 4];
                acc[i] = fmaf(vv.x, frcp(fmaf(w.x, u.x, 1.f)), acc[i]);
                acc[i] = fmaf(vv.y, frcp(fmaf(w.y, u.y, 1.f)), acc[i]);
                acc[i] = fmaf(vv.z, frcp(fmaf(w.z, u.z, 1.f)), acc[i]);
                acc[i] = fmaf(vv.w, frcp(fmaf(w.w, u.w, 1.f)), acc[i]);
            }
        }
    }

    float* dst = part + (size_t)quar * (BB * TD * TE);
    float4 o; o.x = acc[0]; o.y = acc[1]; o.z = acc[2]; o.w = acc[3];
    *(float4*)&dst[((long long)b * TD + d0 + dg) * TE + tt0 + tg * 4] = o;
}

// ---------------------------------------------------------------------------
// Row softmax over 4 summed partials -> e (fp32) + optional A-k8 bf16 split
// ---------------------------------------------------------------------------
__global__ __launch_bounds__(256)
void softmax_rows(const float* __restrict__ part, float* __restrict__ e,
                  unsigned short* __restrict__ H, unsigned short* __restrict__ L)
{
    const int lane = threadIdx.x & 63;
    const int wave = threadIdx.x >> 6;
    const long long row = blockIdx.x * 4 + wave;

    float4 a = {0.f, 0.f, 0.f, 0.f}, c = {0.f, 0.f, 0.f, 0.f};
#pragma unroll
    for (int q = 0; q < 4; ++q) {
        const float* p = part + (size_t)q * (BB * TD * TE) + row * TE;
        const float4 aq = *(const float4*)&p[lane * 4];
        const float4 cq = *(const float4*)&p[lane * 4 + 256];
        a.x += aq.x; a.y += aq.y; a.z += aq.z; a.w += aq.w;
        c.x += cq.x; c.y += cq.y; c.z += cq.z; c.w += cq.w;
    }

    float m = fmaxf(fmaxf(fmaxf(a.x, a.y), fmaxf(a.z, a.w)),
                    fmaxf(fmaxf(c.x, c.y), fmaxf(c.z, c.w)));
#pragma unroll
    for (int off = 32; off; off >>= 1) m = fmaxf(m, __shfl_xor(m, off));

    a.x = __expf(a.x - m); a.y = __expf(a.y - m); a.z = __expf(a.z - m); a.w = __expf(a.w - m);
    c.x = __expf(c.x - m); c.y = __expf(c.y - m); c.z = __expf(c.z - m); c.w = __expf(c.w - m);

    float s = (a.x + a.y + a.z + a.w) + (c.x + c.y + c.z + c.w);
#pragma unroll
    for (int off = 32; off; off >>= 1) s += __shfl_xor(s, off);

    const float inv = __fdividef(1.f, s);
    a.x *= inv; a.y *= inv; a.z *= inv; a.w *= inv;
    c.x *= inv; c.y *= inv; c.z *= inv; c.w *= inv;
    float* pe = e + row * TE;
    *(float4*)&pe[lane * 4] = a;
    *(float4*)&pe[lane * 4 + 256] = c;

    if (H) {
        const int b = (int)(row >> 6);
        const int d = (int)(row & 63);
        const size_t base = (size_t)b * (TD * TE);
        ushort4 h, l;
        {
            const int t0 = lane * 4;
            const size_t o = base + ((size_t)(t0 >> 3) * TD + d) * 8 + (t0 & 7);
            split2(a.x, h.x, l.x); split2(a.y, h.y, l.y);
            split2(a.z, h.z, l.z); split2(a.w, h.w, l.w);
            *(ushort4*)&H[o] = h;
            *(ushort4*)&L[o] = l;
        }
        {
            const int t0 = lane * 4 + 256;
            const size_t o = base + ((size_t)(t0 >> 3) * TD + d) * 8 + (t0 & 7);
            split2(c.x, h.x, l.x); split2(c.y, h.y, l.y);
            split2(c.z, h.z, l.z); split2(c.w, h.w, l.w);
            *(ushort4*)&H[o] = h;
            *(ushort4*)&L[o] = l;
        }
    }
}

// ---------------------------------------------------------------------------
extern "C" void kernel_launch(void* const* d_in, const int* in_sizes, int n_in,
                              void* d_out, int out_size, void* d_ws, size_t ws_size,
                              hipStream_t stream)
{
    const float* enc = (const float*)d_in[0];  // [B,TE,HE]
    const float* dec = (const float*)d_in[1];  // [B,TD,HD=HE]
    const float* Wa  = (const float*)d_in[2];  // [HE,HE]
    const float* Ua  = (const float*)d_in[3];  // [HD,HE]
    const float* Va  = (const float*)d_in[4];  // [HE,1] -> flat [HE]

    float* out   = (float*)d_out;
    float* c_out = out;                        // [B,TD,HE]
    float* e_out = out + (size_t)BB * TD * HE; // [B,TD,TE]

    char* w = (char*)d_ws;
    float* Ew  = (float*)(w);                                  // exp2'd Ws (16 MB)
    float* Eu  = (float*)(w + 16777216);                       // exp2'd Uh (2 MB)
    unsigned short* encAh = (unsigned short*)(w + 18874368);   // A-k8 (8 MB each)
    unsigned short* encAl = (unsigned short*)(w + 27262976);
    unsigned short* encTh = (unsigned short*)(w + 35651584);   // B-k8 per batch
    unsigned short* encTl = (unsigned short*)(w + 44040192);
    unsigned short* decAh = (unsigned short*)(w + 52428800);   // 1 MB each
    unsigned short* decAl = (unsigned short*)(w + 53477376);
    unsigned short* WaTh  = (unsigned short*)(w + 54525952);   // 512 KB each
    unsigned short* WaTl  = (unsigned short*)(w + 55050240);
    unsigned short* UaTh  = (unsigned short*)(w + 55574528);
    unsigned short* UaTl  = (unsigned short*)(w + 56098816);
    unsigned short* eh    = (unsigned short*)(w + 56623104);   // 1 MB each
    unsigned short* el    = (unsigned short*)(w + 57671680);
    float* part = (float*)(w + 58720256);                      // 8 MB (4 x 2 MB)
    const size_t REQUIRED = 67108864;

    dim3 blk(256);

    if (ws_size >= REQUIRED) {
        // --- ALL conversions in one launch ---
        split_all<<<dim3(8, 16, 17), blk, 0, stream>>>(
            enc, encAh, encAl, encTh, encTl,
            dec, decAh, decAl, Wa, WaTh, WaTl, Ua, UaTh, UaTl);

        // Ew = exp2(PRESCALE * enc @ W_a), Eu = exp2(PRESCALE * dec @ U_a)
        gemm_ws_uh<<<dim3(4, 72, 1), blk, 0, stream>>>(
            encAh, encAl, WaTh, WaTl, Ew, decAh, decAl, UaTh, UaTl, Eu);

        // raw score partials (h-split x4, XCD-swizzled)
        scores_raw<<<dim3(TE / 32, (TD / 32) * 4, BB), blk, 0, stream>>>(Ew, Eu, Va, part);
        softmax_rows<<<dim3(BB * TD / 4), blk, 0, stream>>>(part, e_out, eh, el);

        // c[b] = e[b] @ enc[b]
        gemm_mfma3<<<dim3(4, 1, BB), blk, 0, stream>>>(
            eh, el, encTh, encTl, c_out, TD, HE, TE,
            (long long)TD * TE, (long long)TE * HE, (long long)TD * HE);
    } else {
        // --- fallback: fp32 path ---
        float* pf = (float*)(w + 18874368);
        gemm_f32<<<dim3(HE / 64, (BB * TE) / 64, 1), blk, 0, stream>>>(
            enc, Wa, Ew, BB * TE, HE, HE, 0, 0, 0, PRESCALE, 1);
        gemm_f32<<<dim3(HE / 64, (BB * TD) / 64, 1), blk, 0, stream>>>(
            dec, Ua, Eu, BB * TD, HE, HE, 0, 0, 0, PRESCALE, 1);
        scores_raw<<<dim3(TE / 32, (TD / 32) * 4, BB), blk, 0, stream>>>(Ew, Eu, Va, pf);
        softmax_rows<<<dim3(BB * TD / 4), blk, 0, stream>>>(pf, e_out, nullptr, nullptr);
        gemm_f32<<<dim3(HE / 64, TD / 64, BB), blk, 0, stream>>>(
            e_out, enc, c_out, TD, HE, TE,
            (long long)TD * TE, (long long)TE * HE, (long long)TD * HE, 1.0f, 0);
    }
}